// Round 25
// baseline (159.526 us; speedup 1.0000x reference)
//
#include <hip/hip_runtime.h>
#include <hip/hip_bf16.h>
#include <cstdint>
#include <cstddef>

// Causal self-attention, B=2 S=2048 E=1024 H=16 D=64.
// Inputs fp32, output fp32, ws intermediates bf16.
// Round 25: attn_v14 = v10 with K fragments read STRAIGHT FROM GLOBAL
// (L1/L2-resident; TCP pipe) instead of LDS. Arithmetic: v10 pushed ~88KB
// per block-iter through the per-CU DS pipe -> 16896 iters = ~40us of DS
// time = the invariant 45us that six scheduling variants couldn't move.
// Removing the K stream (largest DS item: 8KB/wave/iter reads + staging)
// cuts DS traffic ~45%. LDS 32->16KB (V dbuf only); P in dead V half.
// All other kernels byte-identical to round 24 (113.3us measured).

#define B_  2
#define S_  2048
#define E_  1024
#define NH_ 16
#define DH_ 64
#define M_  (B_*S_)      // 4096
#define F_  (NH_*DH_)    // 1024

typedef unsigned short u16;
typedef short short8 __attribute__((ext_vector_type(8)));
typedef float f32x4  __attribute__((ext_vector_type(4)));

#define QSCALE 0.125f

__device__ __forceinline__ u16 f2bf(float f) {
    union { float f; unsigned int i; } c; c.f = f;
    unsigned int x = c.i;
    x += 0x7fffu + ((x >> 16) & 1u);   // RNE
    return (u16)(x >> 16);
}

// ---------------------------------------------------------------------------
// Merged prep: [0,2048) x fp32->bf16; [2048,2816) wq/wk/wv -> bf16 [n][k];
// [2816,3072) (when launched with 3072 blocks) wo -> wot.
// ---------------------------------------------------------------------------
__global__ __launch_bounds__(256)
void prep(const float* __restrict__ x,
          const float* __restrict__ wq, const float* __restrict__ wk,
          const float* __restrict__ wv, const float* __restrict__ wo,
          u16* __restrict__ xb, u16* __restrict__ Wt, u16* __restrict__ wot)
{
    const int tid = threadIdx.x;
    const int b   = blockIdx.x;
    if (b < 2048) {
        size_t i = (size_t)b * 256 + tid;
        const float4* s = (const float4*)(x + i*8);
        float4 a = s[0], bb = s[1];
        short8 o;
        ((u16*)&o)[0] = f2bf(a.x);  ((u16*)&o)[1] = f2bf(a.y);
        ((u16*)&o)[2] = f2bf(a.z);  ((u16*)&o)[3] = f2bf(a.w);
        ((u16*)&o)[4] = f2bf(bb.x); ((u16*)&o)[5] = f2bf(bb.y);
        ((u16*)&o)[6] = f2bf(bb.z); ((u16*)&o)[7] = f2bf(bb.w);
        ((short8*)xb)[i] = o;
        return;
    }
    __shared__ u16 t[64][66];
    const int wb = b - 2048;
    const int wi = wb >> 8;            // 0..2 = q/k/v, 3 = wo
    const int tt = wb & 255;
    const int n0 = (tt & 15) * 64;
    const int k0 = (tt >> 4) * 64;
    const float* W;
    u16* dst0;
    if (wi < 3) { W = (wi == 0) ? wq : (wi == 1) ? wk : wv;
                  dst0 = Wt + (size_t)wi * E_ * F_; }
    else        { W = wo; dst0 = wot; }

    {
        int kk = tid >> 2, nseg = (tid & 3) * 16;
        const float4* src = (const float4*)(W + (size_t)(k0+kk)*F_ + n0 + nseg);
        #pragma unroll
        for (int v = 0; v < 4; ++v) {
            float4 u = src[v];
            t[kk][nseg + v*4 + 0] = f2bf(u.x);
            t[kk][nseg + v*4 + 1] = f2bf(u.y);
            t[kk][nseg + v*4 + 2] = f2bf(u.z);
            t[kk][nseg + v*4 + 3] = f2bf(u.w);
        }
    }
    __syncthreads();
    {
        int nn = tid >> 2, kseg = (tid & 3) * 16;
        short8 o0, o1;
        #pragma unroll
        for (int i = 0; i < 8; ++i) ((u16*)&o0)[i] = t[kseg + i][nn];
        #pragma unroll
        for (int i = 0; i < 8; ++i) ((u16*)&o1)[i] = t[kseg + 8 + i][nn];
        u16* dst = dst0 + (size_t)(n0+nn)*E_ + k0 + kseg;
        ((short8*)dst)[0] = o0;
        ((short8*)dst)[1] = o1;
    }
}

// ---------------------------------------------------------------------------
// Standalone W transpose (fallback for wo when ws is small).
// ---------------------------------------------------------------------------
__global__ __launch_bounds__(256)
void wtrans(const float* __restrict__ W, u16* __restrict__ Wt)
{
    __shared__ u16 t[64][66];
    const int tid = threadIdx.x;
    const int n0 = blockIdx.x * 64;
    const int k0 = blockIdx.y * 64;
    {
        int kk = tid >> 2, nseg = (tid & 3) * 16;
        const float4* src = (const float4*)(W + (size_t)(k0+kk)*F_ + n0 + nseg);
        #pragma unroll
        for (int v = 0; v < 4; ++v) {
            float4 u = src[v];
            t[kk][nseg + v*4 + 0] = f2bf(u.x);
            t[kk][nseg + v*4 + 1] = f2bf(u.y);
            t[kk][nseg + v*4 + 2] = f2bf(u.z);
            t[kk][nseg + v*4 + 3] = f2bf(u.w);
        }
    }
    __syncthreads();
    {
        int nn = tid >> 2, kseg = (tid & 3) * 16;
        short8 o0, o1;
        #pragma unroll
        for (int i = 0; i < 8; ++i) ((u16*)&o0)[i] = t[kseg + i][nn];
        #pragma unroll
        for (int i = 0; i < 8; ++i) ((u16*)&o1)[i] = t[kseg + 8 + i][nn];
        u16* dst = Wt + (size_t)(n0+nn)*E_ + k0 + kseg;
        ((short8*)dst)[0] = o0;
        ((short8*)dst)[1] = o1;
    }
}

// ---------------------------------------------------------------------------
// bf16 MFMA GEMM via global_load_lds. BM=128, BN=64, BK=64, 4 waves.
// MODE 0: grid 1536 = 16bx*32by*3z; MODE 2: grid 512. XCD-local decode.
// ---------------------------------------------------------------------------
template<int MODE>
__global__ __launch_bounds__(256)
void gemm_bf16(const u16* __restrict__ A, const u16* __restrict__ Wt,
               void* __restrict__ Out0, void* __restrict__ Out1,
               void* __restrict__ Out2)
{
    __shared__ __align__(16) char lds[24576];
    char* lA = lds;            // 128 rows * 128 B
    char* lB = lds + 16384;    // 64 n * 128 B

    const int tid  = threadIdx.x;
    const int lane = tid & 63;
    const int w    = tid >> 6;
    const int wr   = w >> 1, wc = w & 1;
    const int g    = lane >> 4;
    const int q15  = lane & 15;

    const int lin = blockIdx.x;
    const int j   = lin >> 3, xc = lin & 7;
    const int bx  = ((xc >> 2) << 3) + (j & 7);          // [0,16)
    const int by  = ((xc & 3) << 3) + ((j >> 3) & 7);    // [0,32)
    const int z   = j >> 6;                              // [0,3) M0; 0 M2

    const u16* Wz  = Wt + (size_t)z * E_ * F_;
    void*      Out = (z == 0) ? Out0 : (z == 1) ? Out1 : Out2;
    const float osc = (MODE == 0 && z == 0) ? QSCALE : 1.0f;

    const int lr  = lane >> 3;
    const int lc  = lane & 7;
    const int swz = ((lc ^ lr) << 4);

    const int b2 = by >> 4;
    const int s0 = (by & 15) * 128;

    f32x4 acc[4][2];
    #pragma unroll
    for (int i = 0; i < 4; ++i)
        #pragma unroll
        for (int jj = 0; jj < 2; ++jj) acc[i][jj] = (f32x4){0.f,0.f,0.f,0.f};

    for (int it = 0; it < E_/64; ++it) {
        const int k0 = it * 64;
        __syncthreads();
        #pragma unroll
        for (int i = 0; i < 4; ++i) {
            const int row = w*32 + i*8 + lr;
            const char* ga;
            if (MODE == 0) {
                ga = (const char*)A + (size_t)(by*128 + row)*2048 + k0*2 + swz;
            } else {
                const int h = k0 >> 6;
                ga = (const char*)A +
                     ((size_t)(b2*NH_ + h)*S_ + s0 + row)*128 + swz;
            }
            __builtin_amdgcn_global_load_lds(
                (const unsigned int*)ga,
                (unsigned int*)(lA + w*4096 + i*1024), 16, 0, 0);
        }
        #pragma unroll
        for (int i = 0; i < 2; ++i) {
            const int row = w*16 + i*8 + lr;
            const char* gb = (const char*)Wz + (size_t)(bx*64 + row)*2048
                             + k0*2 + swz;
            __builtin_amdgcn_global_load_lds(
                (const unsigned int*)gb,
                (unsigned int*)(lB + w*2048 + i*1024), 16, 0, 0);
        }
        __syncthreads();

        #pragma unroll
        for (int s = 0; s < 2; ++s) {
            short8 af[4], bfr[2];
            #pragma unroll
            for (int mt = 0; mt < 4; ++mt) {
                int row = wr*64 + mt*16 + q15;
                af[mt] = *(const short8*)(lA + row*128 + ((s*64 + 16*g) ^ ((row&7)<<4)));
            }
            #pragma unroll
            for (int nt = 0; nt < 2; ++nt) {
                int n = wc*32 + nt*16 + q15;
                bfr[nt] = *(const short8*)(lB + n*128 + ((s*64 + 16*g) ^ ((n&7)<<4)));
            }
            #pragma unroll
            for (int mt = 0; mt < 4; ++mt)
                #pragma unroll
                for (int nt = 0; nt < 2; ++nt)
                    acc[mt][nt] = __builtin_amdgcn_mfma_f32_16x16x32_bf16(
                        af[mt], bfr[nt], acc[mt][nt], 0, 0, 0);
        }
    }

    #pragma unroll
    for (int mt = 0; mt < 4; ++mt) {
        #pragma unroll
        for (int r = 0; r < 4; ++r) {
            int grow = by*128 + wr*64 + mt*16 + 4*g + r;
            if (MODE == 0) {
                int bb = grow >> 11, ss = grow & (S_-1);
                #pragma unroll
                for (int nt = 0; nt < 2; ++nt) {
                    int n = bx*64 + wc*32 + nt*16 + q15;
                    int hh = n >> 6, dd = n & 63;
                    ((u16*)Out)[(((size_t)bb*NH_ + hh)*S_ + ss)*DH_ + dd] =
                        f2bf(acc[mt][nt][r] * osc);
                }
            } else {
                #pragma unroll
                for (int nt = 0; nt < 2; ++nt) {
                    int n = bx*64 + wc*32 + nt*16 + q15;
                    ((float*)Out)[(size_t)grow * F_ + n] = acc[mt][nt][r];
                }
            }
        }
    }
}

// ---------------------------------------------------------------------------
// V transpose: [b][h][s][d] -> Vt [b][h][d][s] (unchanged, verified).
// ---------------------------------------------------------------------------
__global__ __launch_bounds__(256)
void vtrans(const u16* __restrict__ V, u16* __restrict__ Vt)
{
    __shared__ u16 t[64][66];
    const int tid = threadIdx.x;
    const int st  = blockIdx.x;
    const int bh  = blockIdx.y;

    {
        int s = tid >> 2, dseg = (tid & 3) * 16;
        const u16* src = V + ((size_t)bh*S_ + st*64 + s)*DH_ + dseg;
        short8 a = ((const short8*)src)[0];
        short8 b = ((const short8*)src)[1];
        *(short8*)&t[s][dseg]     = a;
        *(short8*)&t[s][dseg + 8] = b;
    }
    __syncthreads();
    {
        int d = tid >> 2, sseg = (tid & 3) * 16;
        short8 o0, o1;
        #pragma unroll
        for (int i = 0; i < 8; ++i) ((u16*)&o0)[i] = t[sseg + i][d];
        #pragma unroll
        for (int i = 0; i < 8; ++i) ((u16*)&o1)[i] = t[sseg + 8 + i][d];
        u16* dst = Vt + ((size_t)bh*DH_ + d)*S_ + st*64 + sseg;
        ((short8*)dst)[0] = o0;
        ((short8*)dst)[1] = o1;
    }
}

// ---------------------------------------------------------------------------
// attn_v14: v10 structure, K fragments from GLOBAL (TCP pipe), V^T in
// double-buffered LDS (DS pipe), P in the dead V half. Max-free softmax,
// LPT order, cross-iteration V pipeline, one barrier/iter.
// ---------------------------------------------------------------------------
__global__ __launch_bounds__(256)
void attn_v14(const u16* Q, const u16* __restrict__ K,
              const u16* __restrict__ Vt, u16* O)
{
    __shared__ __align__(16) char vls[2*8192];   // V^T tiles; dead half = P

    const int tid  = threadIdx.x;
    const int lane = tid & 63;
    const int w    = tid >> 6;
    const int g    = lane >> 4;
    const int q15  = lane & 15;

    const int blk = blockIdx.x;
    const int qg  = 31 - (blk >> 5);   // LPT: heavy first
    const int bh  = blk & 31;
    const int q0  = qg * 64;

    const u16* Kb  = K  + (size_t)bh * S_ * DH_;
    const u16* Vtb = Vt + (size_t)bh * DH_ * S_;

    short8 qf0, qf1;
    {
        const u16* Qp = Q + ((size_t)bh * S_ + q0 + w*16 + q15) * DH_ + g*8;
        qf0 = *(const short8*)(Qp);
        qf1 = *(const short8*)(Qp + 32);
    }

    f32x4 o[4];
    #pragma unroll
    for (int dt = 0; dt < 4; ++dt) o[dt] = (f32x4){0.f,0.f,0.f,0.f};
    float lrow = 0.f;

    const int sd = tid >> 2;           // V staging d-row 0..63
    const int sk = (tid & 3) * 32;     // byte offset in the 128B row

    short8 svv0, svv1;
    auto LOADV = [&](int t) {
        const u16* vs = Vtb + (size_t)sd * S_ + t*64 + (sk >> 1);
        svv0 = ((const short8*)vs)[0];
        svv1 = ((const short8*)vs)[1];
    };
    auto WRITEV = [&](int buf) {
        char* vdst = vls + buf*8192 + sd*128;
        *(short8*)(vdst + ((sk     ) ^ ((sd&7)<<4))) = svv0;
        *(short8*)(vdst + ((sk + 16) ^ ((sd&7)<<4))) = svv1;
    };

    LOADV(0);
    WRITEV(0);
    __syncthreads();

    for (int kt = 0; ; ++kt) {
        const bool more = (kt < qg);
        if (more) LOADV(kt + 1);       // next V tile -> regs (T14)

        const int cur = kt & 1;
        const char* vt_ = vls + cur * 8192;
        char* plw = vls + (cur ^ 1) * 8192 + w * 2048;  // dead V half

        // ---- QK^T: K fragments straight from global (L1/L2-resident) ----
        const u16* Kp = Kb + (size_t)(kt*64 + q15) * DH_ + g*8;
        float p[16];
        __builtin_amdgcn_s_setprio(1);
        #pragma unroll
        for (int t = 0; t < 4; ++t) {
            short8 kf0 = *(const short8*)(Kp + (size_t)t*16*DH_);
            short8 kf1 = *(const short8*)(Kp + (size_t)t*16*DH_ + 32);
            f32x4 st = (f32x4){0.f,0.f,0.f,0.f};
            st = __builtin_amdgcn_mfma_f32_16x16x32_bf16(kf0, qf0, st, 0, 0, 0);
            st = __builtin_amdgcn_mfma_f32_16x16x32_bf16(kf1, qf1, st, 0, 0, 0);
            #pragma unroll
            for (int r2 = 0; r2 < 4; ++r2) p[t*4+r2] = st[r2];   // Q pre-scaled
        }
        __builtin_amdgcn_s_setprio(0);

        if (kt == qg) {   // diagonal tile
            #pragma unroll
            for (int t = 0; t < 4; ++t)
                #pragma unroll
                for (int r = 0; r < 4; ++r)
                    if (16*t + 4*g + r > w*16 + q15) p[t*4+r] = -1e30f;
        }

        // max-free softmax numerators (|s| << 88, o/l cancels scale)
        float psum = 0.f;
        #pragma unroll
        for (int i = 0; i < 16; ++i) { p[i] = __expf(p[i]); psum += p[i]; }
        psum += __shfl_xor(psum, 16);
        psum += __shfl_xor(psum, 32);
        lrow += psum;

        #pragma unroll
        for (int t = 0; t < 4; ++t) {
            unsigned r0, r1;
            asm("v_cvt_pk_bf16_f32 %0, %1, %2"
                : "=v"(r0) : "v"(p[t*4+0]), "v"(p[t*4+1]));
            asm("v_cvt_pk_bf16_f32 %0, %1, %2"
                : "=v"(r1) : "v"(p[t*4+2]), "v"(p[t*4+3]));
            int byte = q15*128 + ((32*t + 8*g) ^ ((q15&7)<<4));
            uint2 pk; pk.x = r0; pk.y = r1;
            *(uint2*)(plw + byte) = pk;
        }

        __builtin_amdgcn_s_setprio(1);
        #pragma unroll
        for (int c = 0; c < 2; ++c) {
            int pb = q15*128 + ((64*c + 16*g) ^ ((q15&7)<<4));
            short8 pf = *(const short8*)(plw + pb);
            #pragma unroll
            for (int dt = 0; dt < 4; ++dt) {
                int d = dt*16 + q15;
                int vb = d*128 + ((64*c + 16*g) ^ ((d&7)<<4));
                short8 vf = *(const short8*)(vt_ + vb);
                o[dt] = __builtin_amdgcn_mfma_f32_16x16x32_bf16(pf, vf, o[dt], 0, 0, 0);
            }
        }
        __builtin_amdgcn_s_setprio(0);

        if (!more) break;
        WRITEV(cur ^ 1);               // overwrites this iteration's P (consumed)
        __syncthreads();
    }

    float inv = 1.f / lrow;
    #pragma unroll
    for (int r = 0; r < 4; ++r) {
        float li = __shfl(inv, 4*g + r);
        int qrow = q0 + w*16 + 4*g + r;
        #pragma unroll
        for (int dt = 0; dt < 4; ++dt) {
            O[((size_t)bh * S_ + qrow) * DH_ + dt*16 + q15] = f2bf(o[dt][r] * li);
        }
    }
}

// ---------------------------------------------------------------------------
// Scratch: ws = Qw|Kw|Vw (24 MiB) [+ wo^T at 24MB if ws_size allows];
// d_out = D0 (Wt_qkv then Vt) | xb (x_bf16).
// ---------------------------------------------------------------------------
extern "C" void kernel_launch(void* const* d_in, const int* in_sizes, int n_in,
                              void* d_out, int out_size, void* d_ws, size_t ws_size,
                              hipStream_t stream) {
    (void)in_sizes; (void)n_in; (void)out_size;
    const float* x  = (const float*)d_in[0];
    const float* wq = (const float*)d_in[1];
    const float* wk = (const float*)d_in[2];
    const float* wv = (const float*)d_in[3];
    const float* wo = (const float*)d_in[4];

    u16* Qw = (u16*)d_ws;
    u16* Kw = Qw + (size_t)M_ * F_;
    u16* Vw = Kw + (size_t)M_ * F_;

    u16* D0 = (u16*)d_out;
    u16* xb = D0 + (size_t)4*1024*1024;

    const bool bigws = ws_size >= ((size_t)27 << 20);
    u16* wot = bigws ? (u16*)((char*)d_ws + ((size_t)24 << 20)) : Vw;

    prep<<<dim3(bigws ? 3072 : 2816), 256, 0, stream>>>(
        x, wq, wk, wv, wo, xb, D0, wot);

    gemm_bf16<0><<<dim3(1536), 256, 0, stream>>>(
        xb, D0, (void*)Qw, (void*)Kw, (void*)Vw);

    vtrans<<<dim3(S_/64, B_*NH_), 256, 0, stream>>>(Vw, D0);
    if (!bigws)
        wtrans<<<dim3(16,16), 256, 0, stream>>>(wo, Vw);

    attn_v14<<<dim3(B_*NH_*(S_/64)), 256, 0, stream>>>(Qw, Kw, D0, Qw);

    gemm_bf16<2><<<dim3(512), 256, 0, stream>>>(
        Qw, wot, d_out, d_out, d_out);
}

// Round 26
// 158.780 us; speedup vs baseline: 1.0047x; 1.0047x over previous
//
#include <hip/hip_runtime.h>
#include <hip/hip_bf16.h>
#include <cstdint>
#include <cstddef>

// Causal self-attention, B=2 S=2048 E=1024 H=16 D=64.
// Inputs fp32, output fp32, ws intermediates bf16.
// Round 25: attn_v14 = v10 with K fragments read STRAIGHT FROM GLOBAL
// (L1/L2-resident; TCP pipe) instead of LDS. Arithmetic: v10 pushed ~88KB
// per block-iter through the per-CU DS pipe -> 16896 iters = ~40us of DS
// time = the invariant 45us that six scheduling variants couldn't move.
// Removing the K stream (largest DS item: 8KB/wave/iter reads + staging)
// cuts DS traffic ~45%. LDS 32->16KB (V dbuf only); P in dead V half.
// All other kernels byte-identical to round 24 (113.3us measured).

#define B_  2
#define S_  2048
#define E_  1024
#define NH_ 16
#define DH_ 64
#define M_  (B_*S_)      // 4096
#define F_  (NH_*DH_)    // 1024

typedef unsigned short u16;
typedef short short8 __attribute__((ext_vector_type(8)));
typedef float f32x4  __attribute__((ext_vector_type(4)));

#define QSCALE 0.125f

__device__ __forceinline__ u16 f2bf(float f) {
    union { float f; unsigned int i; } c; c.f = f;
    unsigned int x = c.i;
    x += 0x7fffu + ((x >> 16) & 1u);   // RNE
    return (u16)(x >> 16);
}

// ---------------------------------------------------------------------------
// Merged prep: [0,2048) x fp32->bf16; [2048,2816) wq/wk/wv -> bf16 [n][k];
// [2816,3072) (when launched with 3072 blocks) wo -> wot.
// ---------------------------------------------------------------------------
__global__ __launch_bounds__(256)
void prep(const float* __restrict__ x,
          const float* __restrict__ wq, const float* __restrict__ wk,
          const float* __restrict__ wv, const float* __restrict__ wo,
          u16* __restrict__ xb, u16* __restrict__ Wt, u16* __restrict__ wot)
{
    const int tid = threadIdx.x;
    const int b   = blockIdx.x;
    if (b < 2048) {
        size_t i = (size_t)b * 256 + tid;
        const float4* s = (const float4*)(x + i*8);
        float4 a = s[0], bb = s[1];
        short8 o;
        ((u16*)&o)[0] = f2bf(a.x);  ((u16*)&o)[1] = f2bf(a.y);
        ((u16*)&o)[2] = f2bf(a.z);  ((u16*)&o)[3] = f2bf(a.w);
        ((u16*)&o)[4] = f2bf(bb.x); ((u16*)&o)[5] = f2bf(bb.y);
        ((u16*)&o)[6] = f2bf(bb.z); ((u16*)&o)[7] = f2bf(bb.w);
        ((short8*)xb)[i] = o;
        return;
    }
    __shared__ u16 t[64][66];
    const int wb = b - 2048;
    const int wi = wb >> 8;            // 0..2 = q/k/v, 3 = wo
    const int tt = wb & 255;
    const int n0 = (tt & 15) * 64;
    const int k0 = (tt >> 4) * 64;
    const float* W;
    u16* dst0;
    if (wi < 3) { W = (wi == 0) ? wq : (wi == 1) ? wk : wv;
                  dst0 = Wt + (size_t)wi * E_ * F_; }
    else        { W = wo; dst0 = wot; }

    {
        int kk = tid >> 2, nseg = (tid & 3) * 16;
        const float4* src = (const float4*)(W + (size_t)(k0+kk)*F_ + n0 + nseg);
        #pragma unroll
        for (int v = 0; v < 4; ++v) {
            float4 u = src[v];
            t[kk][nseg + v*4 + 0] = f2bf(u.x);
            t[kk][nseg + v*4 + 1] = f2bf(u.y);
            t[kk][nseg + v*4 + 2] = f2bf(u.z);
            t[kk][nseg + v*4 + 3] = f2bf(u.w);
        }
    }
    __syncthreads();
    {
        int nn = tid >> 2, kseg = (tid & 3) * 16;
        short8 o0, o1;
        #pragma unroll
        for (int i = 0; i < 8; ++i) ((u16*)&o0)[i] = t[kseg + i][nn];
        #pragma unroll
        for (int i = 0; i < 8; ++i) ((u16*)&o1)[i] = t[kseg + 8 + i][nn];
        u16* dst = dst0 + (size_t)(n0+nn)*E_ + k0 + kseg;
        ((short8*)dst)[0] = o0;
        ((short8*)dst)[1] = o1;
    }
}

// ---------------------------------------------------------------------------
// Standalone W transpose (fallback for wo when ws is small).
// ---------------------------------------------------------------------------
__global__ __launch_bounds__(256)
void wtrans(const float* __restrict__ W, u16* __restrict__ Wt)
{
    __shared__ u16 t[64][66];
    const int tid = threadIdx.x;
    const int n0 = blockIdx.x * 64;
    const int k0 = blockIdx.y * 64;
    {
        int kk = tid >> 2, nseg = (tid & 3) * 16;
        const float4* src = (const float4*)(W + (size_t)(k0+kk)*F_ + n0 + nseg);
        #pragma unroll
        for (int v = 0; v < 4; ++v) {
            float4 u = src[v];
            t[kk][nseg + v*4 + 0] = f2bf(u.x);
            t[kk][nseg + v*4 + 1] = f2bf(u.y);
            t[kk][nseg + v*4 + 2] = f2bf(u.z);
            t[kk][nseg + v*4 + 3] = f2bf(u.w);
        }
    }
    __syncthreads();
    {
        int nn = tid >> 2, kseg = (tid & 3) * 16;
        short8 o0, o1;
        #pragma unroll
        for (int i = 0; i < 8; ++i) ((u16*)&o0)[i] = t[kseg + i][nn];
        #pragma unroll
        for (int i = 0; i < 8; ++i) ((u16*)&o1)[i] = t[kseg + 8 + i][nn];
        u16* dst = Wt + (size_t)(n0+nn)*E_ + k0 + kseg;
        ((short8*)dst)[0] = o0;
        ((short8*)dst)[1] = o1;
    }
}

// ---------------------------------------------------------------------------
// bf16 MFMA GEMM via global_load_lds. BM=128, BN=64, BK=64, 4 waves.
// MODE 0: grid 1536 = 16bx*32by*3z; MODE 2: grid 512. XCD-local decode.
// ---------------------------------------------------------------------------
template<int MODE>
__global__ __launch_bounds__(256)
void gemm_bf16(const u16* __restrict__ A, const u16* __restrict__ Wt,
               void* __restrict__ Out0, void* __restrict__ Out1,
               void* __restrict__ Out2)
{
    __shared__ __align__(16) char lds[24576];
    char* lA = lds;            // 128 rows * 128 B
    char* lB = lds + 16384;    // 64 n * 128 B

    const int tid  = threadIdx.x;
    const int lane = tid & 63;
    const int w    = tid >> 6;
    const int wr   = w >> 1, wc = w & 1;
    const int g    = lane >> 4;
    const int q15  = lane & 15;

    const int lin = blockIdx.x;
    const int j   = lin >> 3, xc = lin & 7;
    const int bx  = ((xc >> 2) << 3) + (j & 7);          // [0,16)
    const int by  = ((xc & 3) << 3) + ((j >> 3) & 7);    // [0,32)
    const int z   = j >> 6;                              // [0,3) M0; 0 M2

    const u16* Wz  = Wt + (size_t)z * E_ * F_;
    void*      Out = (z == 0) ? Out0 : (z == 1) ? Out1 : Out2;
    const float osc = (MODE == 0 && z == 0) ? QSCALE : 1.0f;

    const int lr  = lane >> 3;
    const int lc  = lane & 7;
    const int swz = ((lc ^ lr) << 4);

    const int b2 = by >> 4;
    const int s0 = (by & 15) * 128;

    f32x4 acc[4][2];
    #pragma unroll
    for (int i = 0; i < 4; ++i)
        #pragma unroll
        for (int jj = 0; jj < 2; ++jj) acc[i][jj] = (f32x4){0.f,0.f,0.f,0.f};

    for (int it = 0; it < E_/64; ++it) {
        const int k0 = it * 64;
        __syncthreads();
        #pragma unroll
        for (int i = 0; i < 4; ++i) {
            const int row = w*32 + i*8 + lr;
            const char* ga;
            if (MODE == 0) {
                ga = (const char*)A + (size_t)(by*128 + row)*2048 + k0*2 + swz;
            } else {
                const int h = k0 >> 6;
                ga = (const char*)A +
                     ((size_t)(b2*NH_ + h)*S_ + s0 + row)*128 + swz;
            }
            __builtin_amdgcn_global_load_lds(
                (const unsigned int*)ga,
                (unsigned int*)(lA + w*4096 + i*1024), 16, 0, 0);
        }
        #pragma unroll
        for (int i = 0; i < 2; ++i) {
            const int row = w*16 + i*8 + lr;
            const char* gb = (const char*)Wz + (size_t)(bx*64 + row)*2048
                             + k0*2 + swz;
            __builtin_amdgcn_global_load_lds(
                (const unsigned int*)gb,
                (unsigned int*)(lB + w*2048 + i*1024), 16, 0, 0);
        }
        __syncthreads();

        #pragma unroll
        for (int s = 0; s < 2; ++s) {
            short8 af[4], bfr[2];
            #pragma unroll
            for (int mt = 0; mt < 4; ++mt) {
                int row = wr*64 + mt*16 + q15;
                af[mt] = *(const short8*)(lA + row*128 + ((s*64 + 16*g) ^ ((row&7)<<4)));
            }
            #pragma unroll
            for (int nt = 0; nt < 2; ++nt) {
                int n = wc*32 + nt*16 + q15;
                bfr[nt] = *(const short8*)(lB + n*128 + ((s*64 + 16*g) ^ ((n&7)<<4)));
            }
            #pragma unroll
            for (int mt = 0; mt < 4; ++mt)
                #pragma unroll
                for (int nt = 0; nt < 2; ++nt)
                    acc[mt][nt] = __builtin_amdgcn_mfma_f32_16x16x32_bf16(
                        af[mt], bfr[nt], acc[mt][nt], 0, 0, 0);
        }
    }

    #pragma unroll
    for (int mt = 0; mt < 4; ++mt) {
        #pragma unroll
        for (int r = 0; r < 4; ++r) {
            int grow = by*128 + wr*64 + mt*16 + 4*g + r;
            if (MODE == 0) {
                int bb = grow >> 11, ss = grow & (S_-1);
                #pragma unroll
                for (int nt = 0; nt < 2; ++nt) {
                    int n = bx*64 + wc*32 + nt*16 + q15;
                    int hh = n >> 6, dd = n & 63;
                    ((u16*)Out)[(((size_t)bb*NH_ + hh)*S_ + ss)*DH_ + dd] =
                        f2bf(acc[mt][nt][r] * osc);
                }
            } else {
                #pragma unroll
                for (int nt = 0; nt < 2; ++nt) {
                    int n = bx*64 + wc*32 + nt*16 + q15;
                    ((float*)Out)[(size_t)grow * F_ + n] = acc[mt][nt][r];
                }
            }
        }
    }
}

// ---------------------------------------------------------------------------
// V transpose: [b][h][s][d] -> Vt [b][h][d][s] (unchanged, verified).
// ---------------------------------------------------------------------------
__global__ __launch_bounds__(256)
void vtrans(const u16* __restrict__ V, u16* __restrict__ Vt)
{
    __shared__ u16 t[64][66];
    const int tid = threadIdx.x;
    const int st  = blockIdx.x;
    const int bh  = blockIdx.y;

    {
        int s = tid >> 2, dseg = (tid & 3) * 16;
        const u16* src = V + ((size_t)bh*S_ + st*64 + s)*DH_ + dseg;
        short8 a = ((const short8*)src)[0];
        short8 b = ((const short8*)src)[1];
        *(short8*)&t[s][dseg]     = a;
        *(short8*)&t[s][dseg + 8] = b;
    }
    __syncthreads();
    {
        int d = tid >> 2, sseg = (tid & 3) * 16;
        short8 o0, o1;
        #pragma unroll
        for (int i = 0; i < 8; ++i) ((u16*)&o0)[i] = t[sseg + i][d];
        #pragma unroll
        for (int i = 0; i < 8; ++i) ((u16*)&o1)[i] = t[sseg + 8 + i][d];
        u16* dst = Vt + ((size_t)bh*DH_ + d)*S_ + st*64 + sseg;
        ((short8*)dst)[0] = o0;
        ((short8*)dst)[1] = o1;
    }
}

// ---------------------------------------------------------------------------
// attn_v14: v10 structure, K fragments from GLOBAL (TCP pipe), V^T in
// double-buffered LDS (DS pipe), P in the dead V half. Max-free softmax,
// LPT order, cross-iteration V pipeline, one barrier/iter.
// ---------------------------------------------------------------------------
__global__ __launch_bounds__(256)
void attn_v14(const u16* Q, const u16* __restrict__ K,
              const u16* __restrict__ Vt, u16* O)
{
    __shared__ __align__(16) char vls[2*8192];   // V^T tiles; dead half = P

    const int tid  = threadIdx.x;
    const int lane = tid & 63;
    const int w    = tid >> 6;
    const int g    = lane >> 4;
    const int q15  = lane & 15;

    const int blk = blockIdx.x;
    const int qg  = 31 - (blk >> 5);   // LPT: heavy first
    const int bh  = blk & 31;
    const int q0  = qg * 64;

    const u16* Kb  = K  + (size_t)bh * S_ * DH_;
    const u16* Vtb = Vt + (size_t)bh * DH_ * S_;

    short8 qf0, qf1;
    {
        const u16* Qp = Q + ((size_t)bh * S_ + q0 + w*16 + q15) * DH_ + g*8;
        qf0 = *(const short8*)(Qp);
        qf1 = *(const short8*)(Qp + 32);
    }

    f32x4 o[4];
    #pragma unroll
    for (int dt = 0; dt < 4; ++dt) o[dt] = (f32x4){0.f,0.f,0.f,0.f};
    float lrow = 0.f;

    const int sd = tid >> 2;           // V staging d-row 0..63
    const int sk = (tid & 3) * 32;     // byte offset in the 128B row

    short8 svv0, svv1;
    auto LOADV = [&](int t) {
        const u16* vs = Vtb + (size_t)sd * S_ + t*64 + (sk >> 1);
        svv0 = ((const short8*)vs)[0];
        svv1 = ((const short8*)vs)[1];
    };
    auto WRITEV = [&](int buf) {
        char* vdst = vls + buf*8192 + sd*128;
        *(short8*)(vdst + ((sk     ) ^ ((sd&7)<<4))) = svv0;
        *(short8*)(vdst + ((sk + 16) ^ ((sd&7)<<4))) = svv1;
    };

    LOADV(0);
    WRITEV(0);
    __syncthreads();

    for (int kt = 0; ; ++kt) {
        const bool more = (kt < qg);
        if (more) LOADV(kt + 1);       // next V tile -> regs (T14)

        const int cur = kt & 1;
        const char* vt_ = vls + cur * 8192;
        char* plw = vls + (cur ^ 1) * 8192 + w * 2048;  // dead V half

        // ---- QK^T: K fragments straight from global (L1/L2-resident) ----
        const u16* Kp = Kb + (size_t)(kt*64 + q15) * DH_ + g*8;
        float p[16];
        __builtin_amdgcn_s_setprio(1);
        #pragma unroll
        for (int t = 0; t < 4; ++t) {
            short8 kf0 = *(const short8*)(Kp + (size_t)t*16*DH_);
            short8 kf1 = *(const short8*)(Kp + (size_t)t*16*DH_ + 32);
            f32x4 st = (f32x4){0.f,0.f,0.f,0.f};
            st = __builtin_amdgcn_mfma_f32_16x16x32_bf16(kf0, qf0, st, 0, 0, 0);
            st = __builtin_amdgcn_mfma_f32_16x16x32_bf16(kf1, qf1, st, 0, 0, 0);
            #pragma unroll
            for (int r2 = 0; r2 < 4; ++r2) p[t*4+r2] = st[r2];   // Q pre-scaled
        }
        __builtin_amdgcn_s_setprio(0);

        if (kt == qg) {   // diagonal tile
            #pragma unroll
            for (int t = 0; t < 4; ++t)
                #pragma unroll
                for (int r = 0; r < 4; ++r)
                    if (16*t + 4*g + r > w*16 + q15) p[t*4+r] = -1e30f;
        }

        // max-free softmax numerators (|s| << 88, o/l cancels scale)
        float psum = 0.f;
        #pragma unroll
        for (int i = 0; i < 16; ++i) { p[i] = __expf(p[i]); psum += p[i]; }
        psum += __shfl_xor(psum, 16);
        psum += __shfl_xor(psum, 32);
        lrow += psum;

        #pragma unroll
        for (int t = 0; t < 4; ++t) {
            unsigned r0, r1;
            asm("v_cvt_pk_bf16_f32 %0, %1, %2"
                : "=v"(r0) : "v"(p[t*4+0]), "v"(p[t*4+1]));
            asm("v_cvt_pk_bf16_f32 %0, %1, %2"
                : "=v"(r1) : "v"(p[t*4+2]), "v"(p[t*4+3]));
            int byte = q15*128 + ((32*t + 8*g) ^ ((q15&7)<<4));
            uint2 pk; pk.x = r0; pk.y = r1;
            *(uint2*)(plw + byte) = pk;
        }

        __builtin_amdgcn_s_setprio(1);
        #pragma unroll
        for (int c = 0; c < 2; ++c) {
            int pb = q15*128 + ((64*c + 16*g) ^ ((q15&7)<<4));
            short8 pf = *(const short8*)(plw + pb);
            #pragma unroll
            for (int dt = 0; dt < 4; ++dt) {
                int d = dt*16 + q15;
                int vb = d*128 + ((64*c + 16*g) ^ ((d&7)<<4));
                short8 vf = *(const short8*)(vt_ + vb);
                o[dt] = __builtin_amdgcn_mfma_f32_16x16x32_bf16(pf, vf, o[dt], 0, 0, 0);
            }
        }
        __builtin_amdgcn_s_setprio(0);

        if (!more) break;
        WRITEV(cur ^ 1);               // overwrites this iteration's P (consumed)
        __syncthreads();
    }

    float inv = 1.f / lrow;
    #pragma unroll
    for (int r = 0; r < 4; ++r) {
        float li = __shfl(inv, 4*g + r);
        int qrow = q0 + w*16 + 4*g + r;
        #pragma unroll
        for (int dt = 0; dt < 4; ++dt) {
            O[((size_t)bh * S_ + qrow) * DH_ + dt*16 + q15] = f2bf(o[dt][r] * li);
        }
    }
}

// ---------------------------------------------------------------------------
// Scratch: ws = Qw|Kw|Vw (24 MiB) [+ wo^T at 24MB if ws_size allows];
// d_out = D0 (Wt_qkv then Vt) | xb (x_bf16).
// ---------------------------------------------------------------------------
extern "C" void kernel_launch(void* const* d_in, const int* in_sizes, int n_in,
                              void* d_out, int out_size, void* d_ws, size_t ws_size,
                              hipStream_t stream) {
    (void)in_sizes; (void)n_in; (void)out_size;
    const float* x  = (const float*)d_in[0];
    const float* wq = (const float*)d_in[1];
    const float* wk = (const float*)d_in[2];
    const float* wv = (const float*)d_in[3];
    const float* wo = (const float*)d_in[4];

    u16* Qw = (u16*)d_ws;
    u16* Kw = Qw + (size_t)M_ * F_;
    u16* Vw = Kw + (size_t)M_ * F_;

    u16* D0 = (u16*)d_out;
    u16* xb = D0 + (size_t)4*1024*1024;

    const bool bigws = ws_size >= ((size_t)27 << 20);
    u16* wot = bigws ? (u16*)((char*)d_ws + ((size_t)24 << 20)) : Vw;

    prep<<<dim3(bigws ? 3072 : 2816), 256, 0, stream>>>(
        x, wq, wk, wv, wo, xb, D0, wot);

    gemm_bf16<0><<<dim3(1536), 256, 0, stream>>>(
        xb, D0, (void*)Qw, (void*)Kw, (void*)Vw);

    vtrans<<<dim3(S_/64, B_*NH_), 256, 0, stream>>>(Vw, D0);
    if (!bigws)
        wtrans<<<dim3(16,16), 256, 0, stream>>>(wo, Vw);

    attn_v14<<<dim3(B_*NH_*(S_/64)), 256, 0, stream>>>(Qw, Kw, D0, Qw);

    gemm_bf16<2><<<dim3(512), 256, 0, stream>>>(
        Qw, wot, d_out, d_out, d_out);
}

// Round 27
// 144.768 us; speedup vs baseline: 1.1019x; 1.0968x over previous
//
#include <hip/hip_runtime.h>
#include <hip/hip_bf16.h>
#include <cstdint>
#include <cstddef>

// Causal self-attention, B=2 S=2048 E=1024 H=16 D=64.
// Inputs fp32, output fp32, ws intermediates bf16.
// Round 27: attn_v15 = v14 (K off the DS pipe) + restored prefetch distance:
// QK^T consumes kf[8] (loaded LAST iteration), then LOADK(kt+1) re-fills the
// same regs with softmax+PV+barrier (~800cy) to hide L1/L2 latency. v14's
// 94us showed latency-hiding dominates; v10's 45us had prefetch but paid
// ~2x DS traffic. This variant has both: prefetched K, halved DS traffic.
// All other kernels byte-identical to round 24/26.

#define B_  2
#define S_  2048
#define E_  1024
#define NH_ 16
#define DH_ 64
#define M_  (B_*S_)      // 4096
#define F_  (NH_*DH_)    // 1024

typedef unsigned short u16;
typedef short short8 __attribute__((ext_vector_type(8)));
typedef float f32x4  __attribute__((ext_vector_type(4)));

#define QSCALE 0.125f

__device__ __forceinline__ u16 f2bf(float f) {
    union { float f; unsigned int i; } c; c.f = f;
    unsigned int x = c.i;
    x += 0x7fffu + ((x >> 16) & 1u);   // RNE
    return (u16)(x >> 16);
}

// ---------------------------------------------------------------------------
// Merged prep: [0,2048) x fp32->bf16; [2048,2816) wq/wk/wv -> bf16 [n][k];
// [2816,3072) (when launched with 3072 blocks) wo -> wot.
// ---------------------------------------------------------------------------
__global__ __launch_bounds__(256)
void prep(const float* __restrict__ x,
          const float* __restrict__ wq, const float* __restrict__ wk,
          const float* __restrict__ wv, const float* __restrict__ wo,
          u16* __restrict__ xb, u16* __restrict__ Wt, u16* __restrict__ wot)
{
    const int tid = threadIdx.x;
    const int b   = blockIdx.x;
    if (b < 2048) {
        size_t i = (size_t)b * 256 + tid;
        const float4* s = (const float4*)(x + i*8);
        float4 a = s[0], bb = s[1];
        short8 o;
        ((u16*)&o)[0] = f2bf(a.x);  ((u16*)&o)[1] = f2bf(a.y);
        ((u16*)&o)[2] = f2bf(a.z);  ((u16*)&o)[3] = f2bf(a.w);
        ((u16*)&o)[4] = f2bf(bb.x); ((u16*)&o)[5] = f2bf(bb.y);
        ((u16*)&o)[6] = f2bf(bb.z); ((u16*)&o)[7] = f2bf(bb.w);
        ((short8*)xb)[i] = o;
        return;
    }
    __shared__ u16 t[64][66];
    const int wb = b - 2048;
    const int wi = wb >> 8;            // 0..2 = q/k/v, 3 = wo
    const int tt = wb & 255;
    const int n0 = (tt & 15) * 64;
    const int k0 = (tt >> 4) * 64;
    const float* W;
    u16* dst0;
    if (wi < 3) { W = (wi == 0) ? wq : (wi == 1) ? wk : wv;
                  dst0 = Wt + (size_t)wi * E_ * F_; }
    else        { W = wo; dst0 = wot; }

    {
        int kk = tid >> 2, nseg = (tid & 3) * 16;
        const float4* src = (const float4*)(W + (size_t)(k0+kk)*F_ + n0 + nseg);
        #pragma unroll
        for (int v = 0; v < 4; ++v) {
            float4 u = src[v];
            t[kk][nseg + v*4 + 0] = f2bf(u.x);
            t[kk][nseg + v*4 + 1] = f2bf(u.y);
            t[kk][nseg + v*4 + 2] = f2bf(u.z);
            t[kk][nseg + v*4 + 3] = f2bf(u.w);
        }
    }
    __syncthreads();
    {
        int nn = tid >> 2, kseg = (tid & 3) * 16;
        short8 o0, o1;
        #pragma unroll
        for (int i = 0; i < 8; ++i) ((u16*)&o0)[i] = t[kseg + i][nn];
        #pragma unroll
        for (int i = 0; i < 8; ++i) ((u16*)&o1)[i] = t[kseg + 8 + i][nn];
        u16* dst = dst0 + (size_t)(n0+nn)*E_ + k0 + kseg;
        ((short8*)dst)[0] = o0;
        ((short8*)dst)[1] = o1;
    }
}

// ---------------------------------------------------------------------------
// Standalone W transpose (fallback for wo when ws is small).
// ---------------------------------------------------------------------------
__global__ __launch_bounds__(256)
void wtrans(const float* __restrict__ W, u16* __restrict__ Wt)
{
    __shared__ u16 t[64][66];
    const int tid = threadIdx.x;
    const int n0 = blockIdx.x * 64;
    const int k0 = blockIdx.y * 64;
    {
        int kk = tid >> 2, nseg = (tid & 3) * 16;
        const float4* src = (const float4*)(W + (size_t)(k0+kk)*F_ + n0 + nseg);
        #pragma unroll
        for (int v = 0; v < 4; ++v) {
            float4 u = src[v];
            t[kk][nseg + v*4 + 0] = f2bf(u.x);
            t[kk][nseg + v*4 + 1] = f2bf(u.y);
            t[kk][nseg + v*4 + 2] = f2bf(u.z);
            t[kk][nseg + v*4 + 3] = f2bf(u.w);
        }
    }
    __syncthreads();
    {
        int nn = tid >> 2, kseg = (tid & 3) * 16;
        short8 o0, o1;
        #pragma unroll
        for (int i = 0; i < 8; ++i) ((u16*)&o0)[i] = t[kseg + i][nn];
        #pragma unroll
        for (int i = 0; i < 8; ++i) ((u16*)&o1)[i] = t[kseg + 8 + i][nn];
        u16* dst = Wt + (size_t)(n0+nn)*E_ + k0 + kseg;
        ((short8*)dst)[0] = o0;
        ((short8*)dst)[1] = o1;
    }
}

// ---------------------------------------------------------------------------
// bf16 MFMA GEMM via global_load_lds. BM=128, BN=64, BK=64, 4 waves.
// MODE 0: grid 1536 = 16bx*32by*3z; MODE 2: grid 512. XCD-local decode.
// ---------------------------------------------------------------------------
template<int MODE>
__global__ __launch_bounds__(256)
void gemm_bf16(const u16* __restrict__ A, const u16* __restrict__ Wt,
               void* __restrict__ Out0, void* __restrict__ Out1,
               void* __restrict__ Out2)
{
    __shared__ __align__(16) char lds[24576];
    char* lA = lds;            // 128 rows * 128 B
    char* lB = lds + 16384;    // 64 n * 128 B

    const int tid  = threadIdx.x;
    const int lane = tid & 63;
    const int w    = tid >> 6;
    const int wr   = w >> 1, wc = w & 1;
    const int g    = lane >> 4;
    const int q15  = lane & 15;

    const int lin = blockIdx.x;
    const int j   = lin >> 3, xc = lin & 7;
    const int bx  = ((xc >> 2) << 3) + (j & 7);          // [0,16)
    const int by  = ((xc & 3) << 3) + ((j >> 3) & 7);    // [0,32)
    const int z   = j >> 6;                              // [0,3) M0; 0 M2

    const u16* Wz  = Wt + (size_t)z * E_ * F_;
    void*      Out = (z == 0) ? Out0 : (z == 1) ? Out1 : Out2;
    const float osc = (MODE == 0 && z == 0) ? QSCALE : 1.0f;

    const int lr  = lane >> 3;
    const int lc  = lane & 7;
    const int swz = ((lc ^ lr) << 4);

    const int b2 = by >> 4;
    const int s0 = (by & 15) * 128;

    f32x4 acc[4][2];
    #pragma unroll
    for (int i = 0; i < 4; ++i)
        #pragma unroll
        for (int jj = 0; jj < 2; ++jj) acc[i][jj] = (f32x4){0.f,0.f,0.f,0.f};

    for (int it = 0; it < E_/64; ++it) {
        const int k0 = it * 64;
        __syncthreads();
        #pragma unroll
        for (int i = 0; i < 4; ++i) {
            const int row = w*32 + i*8 + lr;
            const char* ga;
            if (MODE == 0) {
                ga = (const char*)A + (size_t)(by*128 + row)*2048 + k0*2 + swz;
            } else {
                const int h = k0 >> 6;
                ga = (const char*)A +
                     ((size_t)(b2*NH_ + h)*S_ + s0 + row)*128 + swz;
            }
            __builtin_amdgcn_global_load_lds(
                (const unsigned int*)ga,
                (unsigned int*)(lA + w*4096 + i*1024), 16, 0, 0);
        }
        #pragma unroll
        for (int i = 0; i < 2; ++i) {
            const int row = w*16 + i*8 + lr;
            const char* gb = (const char*)Wz + (size_t)(bx*64 + row)*2048
                             + k0*2 + swz;
            __builtin_amdgcn_global_load_lds(
                (const unsigned int*)gb,
                (unsigned int*)(lB + w*2048 + i*1024), 16, 0, 0);
        }
        __syncthreads();

        #pragma unroll
        for (int s = 0; s < 2; ++s) {
            short8 af[4], bfr[2];
            #pragma unroll
            for (int mt = 0; mt < 4; ++mt) {
                int row = wr*64 + mt*16 + q15;
                af[mt] = *(const short8*)(lA + row*128 + ((s*64 + 16*g) ^ ((row&7)<<4)));
            }
            #pragma unroll
            for (int nt = 0; nt < 2; ++nt) {
                int n = wc*32 + nt*16 + q15;
                bfr[nt] = *(const short8*)(lB + n*128 + ((s*64 + 16*g) ^ ((n&7)<<4)));
            }
            #pragma unroll
            for (int mt = 0; mt < 4; ++mt)
                #pragma unroll
                for (int nt = 0; nt < 2; ++nt)
                    acc[mt][nt] = __builtin_amdgcn_mfma_f32_16x16x32_bf16(
                        af[mt], bfr[nt], acc[mt][nt], 0, 0, 0);
        }
    }

    #pragma unroll
    for (int mt = 0; mt < 4; ++mt) {
        #pragma unroll
        for (int r = 0; r < 4; ++r) {
            int grow = by*128 + wr*64 + mt*16 + 4*g + r;
            if (MODE == 0) {
                int bb = grow >> 11, ss = grow & (S_-1);
                #pragma unroll
                for (int nt = 0; nt < 2; ++nt) {
                    int n = bx*64 + wc*32 + nt*16 + q15;
                    int hh = n >> 6, dd = n & 63;
                    ((u16*)Out)[(((size_t)bb*NH_ + hh)*S_ + ss)*DH_ + dd] =
                        f2bf(acc[mt][nt][r] * osc);
                }
            } else {
                #pragma unroll
                for (int nt = 0; nt < 2; ++nt) {
                    int n = bx*64 + wc*32 + nt*16 + q15;
                    ((float*)Out)[(size_t)grow * F_ + n] = acc[mt][nt][r];
                }
            }
        }
    }
}

// ---------------------------------------------------------------------------
// V transpose: [b][h][s][d] -> Vt [b][h][d][s] (unchanged, verified).
// ---------------------------------------------------------------------------
__global__ __launch_bounds__(256)
void vtrans(const u16* __restrict__ V, u16* __restrict__ Vt)
{
    __shared__ u16 t[64][66];
    const int tid = threadIdx.x;
    const int st  = blockIdx.x;
    const int bh  = blockIdx.y;

    {
        int s = tid >> 2, dseg = (tid & 3) * 16;
        const u16* src = V + ((size_t)bh*S_ + st*64 + s)*DH_ + dseg;
        short8 a = ((const short8*)src)[0];
        short8 b = ((const short8*)src)[1];
        *(short8*)&t[s][dseg]     = a;
        *(short8*)&t[s][dseg + 8] = b;
    }
    __syncthreads();
    {
        int d = tid >> 2, sseg = (tid & 3) * 16;
        short8 o0, o1;
        #pragma unroll
        for (int i = 0; i < 8; ++i) ((u16*)&o0)[i] = t[sseg + i][d];
        #pragma unroll
        for (int i = 0; i < 8; ++i) ((u16*)&o1)[i] = t[sseg + 8 + i][d];
        u16* dst = Vt + ((size_t)bh*DH_ + d)*S_ + st*64 + sseg;
        ((short8*)dst)[0] = o0;
        ((short8*)dst)[1] = o1;
    }
}

// ---------------------------------------------------------------------------
// attn_v15: K from global with one-iteration register prefetch (kf[8] is
// consumed by QK^T, then immediately refilled for kt+1 -> softmax+PV+barrier
// hide the latency). V^T double-buffered in LDS; P in dead V half.
// Max-free softmax, LPT order, one barrier/iter.
// ---------------------------------------------------------------------------
__global__ __launch_bounds__(256)
void attn_v15(const u16* Q, const u16* __restrict__ K,
              const u16* __restrict__ Vt, u16* O)
{
    __shared__ __align__(16) char vls[2*8192];   // V^T tiles; dead half = P

    const int tid  = threadIdx.x;
    const int lane = tid & 63;
    const int w    = tid >> 6;
    const int g    = lane >> 4;
    const int q15  = lane & 15;

    const int blk = blockIdx.x;
    const int qg  = 31 - (blk >> 5);   // LPT: heavy first
    const int bh  = blk & 31;
    const int q0  = qg * 64;

    const u16* Kb  = K  + (size_t)bh * S_ * DH_;
    const u16* Vtb = Vt + (size_t)bh * DH_ * S_;

    short8 qf0, qf1;
    {
        const u16* Qp = Q + ((size_t)bh * S_ + q0 + w*16 + q15) * DH_ + g*8;
        qf0 = *(const short8*)(Qp);
        qf1 = *(const short8*)(Qp + 32);
    }

    f32x4 o[4];
    #pragma unroll
    for (int dt = 0; dt < 4; ++dt) o[dt] = (f32x4){0.f,0.f,0.f,0.f};
    float lrow = 0.f;

    const int sd = tid >> 2;           // V staging d-row 0..63
    const int sk = (tid & 3) * 32;     // byte offset in the 128B row

    short8 svv0, svv1;
    auto LOADV = [&](int t) {
        const u16* vs = Vtb + (size_t)sd * S_ + t*64 + (sk >> 1);
        svv0 = ((const short8*)vs)[0];
        svv1 = ((const short8*)vs)[1];
    };
    auto WRITEV = [&](int buf) {
        char* vdst = vls + buf*8192 + sd*128;
        *(short8*)(vdst + ((sk     ) ^ ((sd&7)<<4))) = svv0;
        *(short8*)(vdst + ((sk + 16) ^ ((sd&7)<<4))) = svv1;
    };

    short8 kf[8];                       // K prefetch registers (one tile ahead)
    auto LOADK = [&](int t) {
        const u16* Kp = Kb + (size_t)(t*64 + q15) * DH_ + g*8;
        #pragma unroll
        for (int i = 0; i < 4; ++i) {
            kf[2*i]   = *(const short8*)(Kp + (size_t)i*16*DH_);
            kf[2*i+1] = *(const short8*)(Kp + (size_t)i*16*DH_ + 32);
        }
    };

    LOADV(0);
    WRITEV(0);
    LOADK(0);
    __syncthreads();

    for (int kt = 0; ; ++kt) {
        const bool more = (kt < qg);
        if (more) LOADV(kt + 1);       // next V tile -> regs

        const int cur = kt & 1;
        const char* vt_ = vls + cur * 8192;
        char* plw = vls + (cur ^ 1) * 8192 + w * 2048;  // dead V half

        // ---- QK^T from prefetched kf (loaded last iteration) ----
        float p[16];
        __builtin_amdgcn_s_setprio(1);
        #pragma unroll
        for (int t = 0; t < 4; ++t) {
            f32x4 st = (f32x4){0.f,0.f,0.f,0.f};
            st = __builtin_amdgcn_mfma_f32_16x16x32_bf16(kf[2*t],   qf0, st, 0, 0, 0);
            st = __builtin_amdgcn_mfma_f32_16x16x32_bf16(kf[2*t+1], qf1, st, 0, 0, 0);
            #pragma unroll
            for (int r2 = 0; r2 < 4; ++r2) p[t*4+r2] = st[r2];   // Q pre-scaled
        }
        __builtin_amdgcn_s_setprio(0);

        if (more) LOADK(kt + 1);       // refill kf; hidden under softmax+PV

        if (kt == qg) {   // diagonal tile
            #pragma unroll
            for (int t = 0; t < 4; ++t)
                #pragma unroll
                for (int r = 0; r < 4; ++r)
                    if (16*t + 4*g + r > w*16 + q15) p[t*4+r] = -1e30f;
        }

        // max-free softmax numerators (|s| << 88, o/l cancels scale)
        float psum = 0.f;
        #pragma unroll
        for (int i = 0; i < 16; ++i) { p[i] = __expf(p[i]); psum += p[i]; }
        psum += __shfl_xor(psum, 16);
        psum += __shfl_xor(psum, 32);
        lrow += psum;

        #pragma unroll
        for (int t = 0; t < 4; ++t) {
            unsigned r0, r1;
            asm("v_cvt_pk_bf16_f32 %0, %1, %2"
                : "=v"(r0) : "v"(p[t*4+0]), "v"(p[t*4+1]));
            asm("v_cvt_pk_bf16_f32 %0, %1, %2"
                : "=v"(r1) : "v"(p[t*4+2]), "v"(p[t*4+3]));
            int byte = q15*128 + ((32*t + 8*g) ^ ((q15&7)<<4));
            uint2 pk; pk.x = r0; pk.y = r1;
            *(uint2*)(plw + byte) = pk;
        }

        __builtin_amdgcn_s_setprio(1);
        #pragma unroll
        for (int c = 0; c < 2; ++c) {
            int pb = q15*128 + ((64*c + 16*g) ^ ((q15&7)<<4));
            short8 pf = *(const short8*)(plw + pb);
            #pragma unroll
            for (int dt = 0; dt < 4; ++dt) {
                int d = dt*16 + q15;
                int vb = d*128 + ((64*c + 16*g) ^ ((d&7)<<4));
                short8 vf = *(const short8*)(vt_ + vb);
                o[dt] = __builtin_amdgcn_mfma_f32_16x16x32_bf16(pf, vf, o[dt], 0, 0, 0);
            }
        }
        __builtin_amdgcn_s_setprio(0);

        if (!more) break;
        WRITEV(cur ^ 1);               // overwrites this iteration's P (consumed)
        __syncthreads();
    }

    float inv = 1.f / lrow;
    #pragma unroll
    for (int r = 0; r < 4; ++r) {
        float li = __shfl(inv, 4*g + r);
        int qrow = q0 + w*16 + 4*g + r;
        #pragma unroll
        for (int dt = 0; dt < 4; ++dt) {
            O[((size_t)bh * S_ + qrow) * DH_ + dt*16 + q15] = f2bf(o[dt][r] * li);
        }
    }
}

// ---------------------------------------------------------------------------
// Scratch: ws = Qw|Kw|Vw (24 MiB) [+ wo^T at 24MB if ws_size allows];
// d_out = D0 (Wt_qkv then Vt) | xb (x_bf16).
// ---------------------------------------------------------------------------
extern "C" void kernel_launch(void* const* d_in, const int* in_sizes, int n_in,
                              void* d_out, int out_size, void* d_ws, size_t ws_size,
                              hipStream_t stream) {
    (void)in_sizes; (void)n_in; (void)out_size;
    const float* x  = (const float*)d_in[0];
    const float* wq = (const float*)d_in[1];
    const float* wk = (const float*)d_in[2];
    const float* wv = (const float*)d_in[3];
    const float* wo = (const float*)d_in[4];

    u16* Qw = (u16*)d_ws;
    u16* Kw = Qw + (size_t)M_ * F_;
    u16* Vw = Kw + (size_t)M_ * F_;

    u16* D0 = (u16*)d_out;
    u16* xb = D0 + (size_t)4*1024*1024;

    const bool bigws = ws_size >= ((size_t)27 << 20);
    u16* wot = bigws ? (u16*)((char*)d_ws + ((size_t)24 << 20)) : Vw;

    prep<<<dim3(bigws ? 3072 : 2816), 256, 0, stream>>>(
        x, wq, wk, wv, wo, xb, D0, wot);

    gemm_bf16<0><<<dim3(1536), 256, 0, stream>>>(
        xb, D0, (void*)Qw, (void*)Kw, (void*)Vw);

    vtrans<<<dim3(S_/64, B_*NH_), 256, 0, stream>>>(Vw, D0);
    if (!bigws)
        wtrans<<<dim3(16,16), 256, 0, stream>>>(wo, Vw);

    attn_v15<<<dim3(B_*NH_*(S_/64)), 256, 0, stream>>>(Qw, Kw, D0, Qw);

    gemm_bf16<2><<<dim3(512), 256, 0, stream>>>(
        Qw, wot, d_out, d_out, d_out);
}

// Round 28
// 113.370 us; speedup vs baseline: 1.4071x; 1.2770x over previous
//
#include <hip/hip_runtime.h>
#include <hip/hip_bf16.h>
#include <cstdint>
#include <cstddef>

// Causal self-attention, B=2 S=2048 E=1024 H=16 D=64.
// Inputs fp32, output fp32, ws intermediates bf16.
// FINAL (round 28) = round-24 configuration, best measured: 113.3us
// (reproduced 113.8/113.3 across two runs). Journey: 1825us naive -> 113us.
// attn_v10 is locally optimal across 9 tested perturbations; v14/v15 showed
// K-in-LDS acts as a bandwidth amplifier (1 global fetch -> 4 wave reads),
// refuting the DS-throughput model that motivated K-direct variants.
// Pipeline: prep (x->bf16 + W^T) -> qkv GEMM (BN=64, gload_lds, XCD-local)
// -> vtrans -> attn_v10 (max-free softmax, P in dead K-buffer, cross-iter
// reg-staged pipeline, LPT) -> oproj GEMM.

#define B_  2
#define S_  2048
#define E_  1024
#define NH_ 16
#define DH_ 64
#define M_  (B_*S_)      // 4096
#define F_  (NH_*DH_)    // 1024

typedef unsigned short u16;
typedef short short8 __attribute__((ext_vector_type(8)));
typedef float f32x4  __attribute__((ext_vector_type(4)));

#define QSCALE 0.125f

__device__ __forceinline__ u16 f2bf(float f) {
    union { float f; unsigned int i; } c; c.f = f;
    unsigned int x = c.i;
    x += 0x7fffu + ((x >> 16) & 1u);   // RNE
    return (u16)(x >> 16);
}

// ---------------------------------------------------------------------------
// Merged prep: [0,2048) x fp32->bf16; [2048,2816) wq/wk/wv -> bf16 [n][k];
// [2816,3072) (when launched with 3072 blocks) wo -> wot.
// ---------------------------------------------------------------------------
__global__ __launch_bounds__(256)
void prep(const float* __restrict__ x,
          const float* __restrict__ wq, const float* __restrict__ wk,
          const float* __restrict__ wv, const float* __restrict__ wo,
          u16* __restrict__ xb, u16* __restrict__ Wt, u16* __restrict__ wot)
{
    const int tid = threadIdx.x;
    const int b   = blockIdx.x;
    if (b < 2048) {
        size_t i = (size_t)b * 256 + tid;
        const float4* s = (const float4*)(x + i*8);
        float4 a = s[0], bb = s[1];
        short8 o;
        ((u16*)&o)[0] = f2bf(a.x);  ((u16*)&o)[1] = f2bf(a.y);
        ((u16*)&o)[2] = f2bf(a.z);  ((u16*)&o)[3] = f2bf(a.w);
        ((u16*)&o)[4] = f2bf(bb.x); ((u16*)&o)[5] = f2bf(bb.y);
        ((u16*)&o)[6] = f2bf(bb.z); ((u16*)&o)[7] = f2bf(bb.w);
        ((short8*)xb)[i] = o;
        return;
    }
    __shared__ u16 t[64][66];
    const int wb = b - 2048;
    const int wi = wb >> 8;            // 0..2 = q/k/v, 3 = wo
    const int tt = wb & 255;
    const int n0 = (tt & 15) * 64;
    const int k0 = (tt >> 4) * 64;
    const float* W;
    u16* dst0;
    if (wi < 3) { W = (wi == 0) ? wq : (wi == 1) ? wk : wv;
                  dst0 = Wt + (size_t)wi * E_ * F_; }
    else        { W = wo; dst0 = wot; }

    {
        int kk = tid >> 2, nseg = (tid & 3) * 16;
        const float4* src = (const float4*)(W + (size_t)(k0+kk)*F_ + n0 + nseg);
        #pragma unroll
        for (int v = 0; v < 4; ++v) {
            float4 u = src[v];
            t[kk][nseg + v*4 + 0] = f2bf(u.x);
            t[kk][nseg + v*4 + 1] = f2bf(u.y);
            t[kk][nseg + v*4 + 2] = f2bf(u.z);
            t[kk][nseg + v*4 + 3] = f2bf(u.w);
        }
    }
    __syncthreads();
    {
        int nn = tid >> 2, kseg = (tid & 3) * 16;
        short8 o0, o1;
        #pragma unroll
        for (int i = 0; i < 8; ++i) ((u16*)&o0)[i] = t[kseg + i][nn];
        #pragma unroll
        for (int i = 0; i < 8; ++i) ((u16*)&o1)[i] = t[kseg + 8 + i][nn];
        u16* dst = dst0 + (size_t)(n0+nn)*E_ + k0 + kseg;
        ((short8*)dst)[0] = o0;
        ((short8*)dst)[1] = o1;
    }
}

// ---------------------------------------------------------------------------
// Standalone W transpose (fallback for wo when ws is small).
// ---------------------------------------------------------------------------
__global__ __launch_bounds__(256)
void wtrans(const float* __restrict__ W, u16* __restrict__ Wt)
{
    __shared__ u16 t[64][66];
    const int tid = threadIdx.x;
    const int n0 = blockIdx.x * 64;
    const int k0 = blockIdx.y * 64;
    {
        int kk = tid >> 2, nseg = (tid & 3) * 16;
        const float4* src = (const float4*)(W + (size_t)(k0+kk)*F_ + n0 + nseg);
        #pragma unroll
        for (int v = 0; v < 4; ++v) {
            float4 u = src[v];
            t[kk][nseg + v*4 + 0] = f2bf(u.x);
            t[kk][nseg + v*4 + 1] = f2bf(u.y);
            t[kk][nseg + v*4 + 2] = f2bf(u.z);
            t[kk][nseg + v*4 + 3] = f2bf(u.w);
        }
    }
    __syncthreads();
    {
        int nn = tid >> 2, kseg = (tid & 3) * 16;
        short8 o0, o1;
        #pragma unroll
        for (int i = 0; i < 8; ++i) ((u16*)&o0)[i] = t[kseg + i][nn];
        #pragma unroll
        for (int i = 0; i < 8; ++i) ((u16*)&o1)[i] = t[kseg + 8 + i][nn];
        u16* dst = Wt + (size_t)(n0+nn)*E_ + k0 + kseg;
        ((short8*)dst)[0] = o0;
        ((short8*)dst)[1] = o1;
    }
}

// ---------------------------------------------------------------------------
// bf16 MFMA GEMM via global_load_lds. BM=128, BN=64, BK=64, 4 waves.
// MODE 0: grid 1536 = 16bx*32by*3z; A = xb rows, scatter-out bf16 (head=bx).
// MODE 2: grid  512 = 16bx*32by;    A = O gather,  row-major fp32 out.
// XCD-local decode: cell = 8bx x 8by (x3z).
// ---------------------------------------------------------------------------
template<int MODE>
__global__ __launch_bounds__(256)
void gemm_bf16(const u16* __restrict__ A, const u16* __restrict__ Wt,
               void* __restrict__ Out0, void* __restrict__ Out1,
               void* __restrict__ Out2)
{
    __shared__ __align__(16) char lds[24576];
    char* lA = lds;            // 128 rows * 128 B
    char* lB = lds + 16384;    // 64 n * 128 B

    const int tid  = threadIdx.x;
    const int lane = tid & 63;
    const int w    = tid >> 6;
    const int wr   = w >> 1, wc = w & 1;
    const int g    = lane >> 4;
    const int q15  = lane & 15;

    const int lin = blockIdx.x;
    const int j   = lin >> 3, xc = lin & 7;
    const int bx  = ((xc >> 2) << 3) + (j & 7);          // [0,16)
    const int by  = ((xc & 3) << 3) + ((j >> 3) & 7);    // [0,32)
    const int z   = j >> 6;                              // [0,3) M0; 0 M2

    const u16* Wz  = Wt + (size_t)z * E_ * F_;
    void*      Out = (z == 0) ? Out0 : (z == 1) ? Out1 : Out2;
    const float osc = (MODE == 0 && z == 0) ? QSCALE : 1.0f;

    const int lr  = lane >> 3;
    const int lc  = lane & 7;
    const int swz = ((lc ^ lr) << 4);

    const int b2 = by >> 4;
    const int s0 = (by & 15) * 128;

    f32x4 acc[4][2];
    #pragma unroll
    for (int i = 0; i < 4; ++i)
        #pragma unroll
        for (int jj = 0; jj < 2; ++jj) acc[i][jj] = (f32x4){0.f,0.f,0.f,0.f};

    for (int it = 0; it < E_/64; ++it) {
        const int k0 = it * 64;
        __syncthreads();
        #pragma unroll
        for (int i = 0; i < 4; ++i) {
            const int row = w*32 + i*8 + lr;
            const char* ga;
            if (MODE == 0) {
                ga = (const char*)A + (size_t)(by*128 + row)*2048 + k0*2 + swz;
            } else {
                const int h = k0 >> 6;
                ga = (const char*)A +
                     ((size_t)(b2*NH_ + h)*S_ + s0 + row)*128 + swz;
            }
            __builtin_amdgcn_global_load_lds(
                (const unsigned int*)ga,
                (unsigned int*)(lA + w*4096 + i*1024), 16, 0, 0);
        }
        #pragma unroll
        for (int i = 0; i < 2; ++i) {
            const int row = w*16 + i*8 + lr;
            const char* gb = (const char*)Wz + (size_t)(bx*64 + row)*2048
                             + k0*2 + swz;
            __builtin_amdgcn_global_load_lds(
                (const unsigned int*)gb,
                (unsigned int*)(lB + w*2048 + i*1024), 16, 0, 0);
        }
        __syncthreads();

        #pragma unroll
        for (int s = 0; s < 2; ++s) {
            short8 af[4], bfr[2];
            #pragma unroll
            for (int mt = 0; mt < 4; ++mt) {
                int row = wr*64 + mt*16 + q15;
                af[mt] = *(const short8*)(lA + row*128 + ((s*64 + 16*g) ^ ((row&7)<<4)));
            }
            #pragma unroll
            for (int nt = 0; nt < 2; ++nt) {
                int n = wc*32 + nt*16 + q15;
                bfr[nt] = *(const short8*)(lB + n*128 + ((s*64 + 16*g) ^ ((n&7)<<4)));
            }
            #pragma unroll
            for (int mt = 0; mt < 4; ++mt)
                #pragma unroll
                for (int nt = 0; nt < 2; ++nt)
                    acc[mt][nt] = __builtin_amdgcn_mfma_f32_16x16x32_bf16(
                        af[mt], bfr[nt], acc[mt][nt], 0, 0, 0);
        }
    }

    #pragma unroll
    for (int mt = 0; mt < 4; ++mt) {
        #pragma unroll
        for (int r = 0; r < 4; ++r) {
            int grow = by*128 + wr*64 + mt*16 + 4*g + r;
            if (MODE == 0) {
                int bb = grow >> 11, ss = grow & (S_-1);
                #pragma unroll
                for (int nt = 0; nt < 2; ++nt) {
                    int n = bx*64 + wc*32 + nt*16 + q15;
                    int hh = n >> 6, dd = n & 63;
                    ((u16*)Out)[(((size_t)bb*NH_ + hh)*S_ + ss)*DH_ + dd] =
                        f2bf(acc[mt][nt][r] * osc);
                }
            } else {
                #pragma unroll
                for (int nt = 0; nt < 2; ++nt) {
                    int n = bx*64 + wc*32 + nt*16 + q15;
                    ((float*)Out)[(size_t)grow * F_ + n] = acc[mt][nt][r];
                }
            }
        }
    }
}

// ---------------------------------------------------------------------------
// V transpose: [b][h][s][d] -> Vt [b][h][d][s].
// ---------------------------------------------------------------------------
__global__ __launch_bounds__(256)
void vtrans(const u16* __restrict__ V, u16* __restrict__ Vt)
{
    __shared__ u16 t[64][66];
    const int tid = threadIdx.x;
    const int st  = blockIdx.x;
    const int bh  = blockIdx.y;

    {
        int s = tid >> 2, dseg = (tid & 3) * 16;
        const u16* src = V + ((size_t)bh*S_ + st*64 + s)*DH_ + dseg;
        short8 a = ((const short8*)src)[0];
        short8 b = ((const short8*)src)[1];
        *(short8*)&t[s][dseg]     = a;
        *(short8*)&t[s][dseg + 8] = b;
    }
    __syncthreads();
    {
        int d = tid >> 2, sseg = (tid & 3) * 16;
        short8 o0, o1;
        #pragma unroll
        for (int i = 0; i < 8; ++i) ((u16*)&o0)[i] = t[sseg + i][d];
        #pragma unroll
        for (int i = 0; i < 8; ++i) ((u16*)&o1)[i] = t[sseg + 8 + i][d];
        u16* dst = Vt + ((size_t)bh*DH_ + d)*S_ + st*64 + sseg;
        ((short8*)dst)[0] = o0;
        ((short8*)dst)[1] = o1;
    }
}

// ---------------------------------------------------------------------------
// attn_v10 (final): max-free softmax (o/l cancels scale; |s| << exp range),
// P in dead K-buffer half, cross-iteration reg-staged K+V pipeline, one
// barrier per KV tile, LPT dispatch order.
// ---------------------------------------------------------------------------
__global__ __launch_bounds__(256)
void attn_v10(const u16* Q, const u16* __restrict__ K,
              const u16* __restrict__ Vt, u16* O)
{
    __shared__ __align__(16) char vls[2*8192];
    __shared__ __align__(16) char kls[2*8192];

    const int tid  = threadIdx.x;
    const int lane = tid & 63;
    const int w    = tid >> 6;
    const int g    = lane >> 4;
    const int q15  = lane & 15;

    const int blk = blockIdx.x;
    const int qg  = 31 - (blk >> 5);
    const int bh  = blk & 31;
    const int q0  = qg * 64;

    const u16* Kb  = K  + (size_t)bh * S_ * DH_;
    const u16* Vtb = Vt + (size_t)bh * DH_ * S_;

    short8 qf0, qf1;
    {
        const u16* Qp = Q + ((size_t)bh * S_ + q0 + w*16 + q15) * DH_ + g*8;
        qf0 = *(const short8*)(Qp);
        qf1 = *(const short8*)(Qp + 32);
    }

    f32x4 o[4];
    #pragma unroll
    for (int dt = 0; dt < 4; ++dt) o[dt] = (f32x4){0.f,0.f,0.f,0.f};
    float lrow = 0.f;

    const int sd = tid >> 2;
    const int sk = (tid & 3) * 32;

    short8 svv0, svv1, svk0, svk1;
    auto LOADX = [&](int t) {
        const u16* vs = Vtb + (size_t)sd * S_ + t*64 + (sk >> 1);
        svv0 = ((const short8*)vs)[0];
        svv1 = ((const short8*)vs)[1];
        const u16* ks = Kb + (size_t)(t*64 + sd) * DH_ + (sk >> 1);
        svk0 = ((const short8*)ks)[0];
        svk1 = ((const short8*)ks)[1];
    };
    auto WRITEX = [&](int buf) {
        char* vdst = vls + buf*8192 + sd*128;
        *(short8*)(vdst + ((sk     ) ^ ((sd&7)<<4))) = svv0;
        *(short8*)(vdst + ((sk + 16) ^ ((sd&7)<<4))) = svv1;
        char* kdst = kls + buf*8192 + sd*128;
        *(short8*)(kdst + ((sk     ) ^ ((sd&7)<<4))) = svk0;
        *(short8*)(kdst + ((sk + 16) ^ ((sd&7)<<4))) = svk1;
    };

    LOADX(0);
    WRITEX(0);
    __syncthreads();

    for (int kt = 0; ; ++kt) {
        const bool more = (kt < qg);
        if (more) LOADX(kt + 1);

        const int cur = kt & 1;
        const char* kt_ = kls + cur * 8192;
        const char* vt_ = vls + cur * 8192;
        char* plw = kls + (cur ^ 1) * 8192 + w * 2048;

        float p[16];
        __builtin_amdgcn_s_setprio(1);
        #pragma unroll
        for (int t = 0; t < 4; ++t) {
            int r = t*16 + q15;
            short8 kf0 = *(const short8*)(kt_ + r*128 + ((16*g     ) ^ ((r&7)<<4)));
            short8 kf1 = *(const short8*)(kt_ + r*128 + ((16*g + 64) ^ ((r&7)<<4)));
            f32x4 st = (f32x4){0.f,0.f,0.f,0.f};
            st = __builtin_amdgcn_mfma_f32_16x16x32_bf16(kf0, qf0, st, 0, 0, 0);
            st = __builtin_amdgcn_mfma_f32_16x16x32_bf16(kf1, qf1, st, 0, 0, 0);
            #pragma unroll
            for (int r2 = 0; r2 < 4; ++r2) p[t*4+r2] = st[r2];
        }
        __builtin_amdgcn_s_setprio(0);

        if (kt == qg) {
            #pragma unroll
            for (int t = 0; t < 4; ++t)
                #pragma unroll
                for (int r = 0; r < 4; ++r)
                    if (16*t + 4*g + r > w*16 + q15) p[t*4+r] = -1e30f;
        }

        float psum = 0.f;
        #pragma unroll
        for (int i = 0; i < 16; ++i) { p[i] = __expf(p[i]); psum += p[i]; }
        psum += __shfl_xor(psum, 16);
        psum += __shfl_xor(psum, 32);
        lrow += psum;

        #pragma unroll
        for (int t = 0; t < 4; ++t) {
            unsigned r0, r1;
            asm("v_cvt_pk_bf16_f32 %0, %1, %2"
                : "=v"(r0) : "v"(p[t*4+0]), "v"(p[t*4+1]));
            asm("v_cvt_pk_bf16_f32 %0, %1, %2"
                : "=v"(r1) : "v"(p[t*4+2]), "v"(p[t*4+3]));
            int byte = q15*128 + ((32*t + 8*g) ^ ((q15&7)<<4));
            uint2 pk; pk.x = r0; pk.y = r1;
            *(uint2*)(plw + byte) = pk;
        }

        __builtin_amdgcn_s_setprio(1);
        #pragma unroll
        for (int c = 0; c < 2; ++c) {
            int pb = q15*128 + ((64*c + 16*g) ^ ((q15&7)<<4));
            short8 pf = *(const short8*)(plw + pb);
            #pragma unroll
            for (int dt = 0; dt < 4; ++dt) {
                int d = dt*16 + q15;
                int vb = d*128 + ((64*c + 16*g) ^ ((d&7)<<4));
                short8 vf = *(const short8*)(vt_ + vb);
                o[dt] = __builtin_amdgcn_mfma_f32_16x16x32_bf16(pf, vf, o[dt], 0, 0, 0);
            }
        }
        __builtin_amdgcn_s_setprio(0);

        if (!more) break;
        WRITEX(cur ^ 1);
        __syncthreads();
    }

    float inv = 1.f / lrow;
    #pragma unroll
    for (int r = 0; r < 4; ++r) {
        float li = __shfl(inv, 4*g + r);
        int qrow = q0 + w*16 + 4*g + r;
        #pragma unroll
        for (int dt = 0; dt < 4; ++dt) {
            O[((size_t)bh * S_ + qrow) * DH_ + dt*16 + q15] = f2bf(o[dt][r] * li);
        }
    }
}

// ---------------------------------------------------------------------------
// Scratch: ws = Qw|Kw|Vw (24 MiB) [+ wo^T at 24MB if ws_size allows];
// d_out = D0 (Wt_qkv then Vt) | xb (x_bf16).
// ---------------------------------------------------------------------------
extern "C" void kernel_launch(void* const* d_in, const int* in_sizes, int n_in,
                              void* d_out, int out_size, void* d_ws, size_t ws_size,
                              hipStream_t stream) {
    (void)in_sizes; (void)n_in; (void)out_size;
    const float* x  = (const float*)d_in[0];
    const float* wq = (const float*)d_in[1];
    const float* wk = (const float*)d_in[2];
    const float* wv = (const float*)d_in[3];
    const float* wo = (const float*)d_in[4];

    u16* Qw = (u16*)d_ws;
    u16* Kw = Qw + (size_t)M_ * F_;
    u16* Vw = Kw + (size_t)M_ * F_;

    u16* D0 = (u16*)d_out;
    u16* xb = D0 + (size_t)4*1024*1024;

    const bool bigws = ws_size >= ((size_t)27 << 20);
    u16* wot = bigws ? (u16*)((char*)d_ws + ((size_t)24 << 20)) : Vw;

    prep<<<dim3(bigws ? 3072 : 2816), 256, 0, stream>>>(
        x, wq, wk, wv, wo, xb, D0, wot);

    gemm_bf16<0><<<dim3(1536), 256, 0, stream>>>(
        xb, D0, (void*)Qw, (void*)Kw, (void*)Vw);

    vtrans<<<dim3(S_/64, B_*NH_), 256, 0, stream>>>(Vw, D0);
    if (!bigws)
        wtrans<<<dim3(16,16), 256, 0, stream>>>(wo, Vw);

    attn_v10<<<dim3(B_*NH_*(S_/64)), 256, 0, stream>>>(Qw, Kw, D0, Qw);

    gemm_bf16<2><<<dim3(512), 256, 0, stream>>>(
        Qw, wot, d_out, d_out, d_out);
}